// Round 9
// baseline (196.077 us; speedup 1.0000x reference)
//
#include <hip/hip_runtime.h>

// GCN: out[m,n,o] = (A_hat relu(A_hat (x W1) + b1) W_out[m])[n,o] + b_out[m,o]
// A_hat = D^-1/2 (A + I) D^-1/2.
// R9 = R7 with the prop1s self-loop double-count fixed (added ONCE, after the
// edge-group reduction).
//  - radix partition by 256-node SUPER-bucket, LDS count-sort -> CSR + dinv.
//  - g = bf16(dinv * (x@W1)) via MFMA split-bf16, stored SLICE-MAJOR
//    (8 slices x 16 cols, slice = 1.6MB -> per-XCD L2-resident).
//  - prop1: block slice = blockIdx&7 (XCD round-robin); fused relu + partial
//    8-col projection into g2part[8][N][8]; finalize sums slices.
//  - prop2 on bf16 g2 (800KB, L2-resident).

constexpr int CIN = 128;
constexpr int SSHIFT = 8;        // 256 nodes per super-bucket
constexpr int NBLKB = 256;       // partition blocks == scan chunk size
constexpr int CSR_CAP = 10240;   // LDS sort capacity (mean ~8163, std ~90)

typedef __attribute__((ext_vector_type(8))) short short8v;
typedef __attribute__((ext_vector_type(4))) float float4v;

__device__ inline unsigned pack_bf16x2(float a, float b) {
  unsigned ua = __float_as_uint(a), ub = __float_as_uint(b);
  ua = (ua + 0x7FFFu + ((ua >> 16) & 1u)) >> 16;
  ub = (ub + 0x7FFFu + ((ub >> 16) & 1u)) >> 16;
  return ua | (ub << 16);
}
__device__ inline float bf_lo(unsigned u) { return __uint_as_float(u << 16); }
__device__ inline float bf_hi(unsigned u) { return __uint_as_float(u & 0xFFFF0000u); }

// ---------- pass A: per-block super-bucket histogram ----------
__global__ __launch_bounds__(256) void histsb_k(const int* __restrict__ dst,
    int* __restrict__ blockhist, int E, int nsb) {
  __shared__ int lh[256];
  int b = blockIdx.x, t = threadIdx.x;
  lh[t] = 0;
  __syncthreads();
  int per = (E + gridDim.x - 1) / gridDim.x;
  int s0 = b * per, s1 = min(E, s0 + per);
  for (int i = s0 + t; i < s1; i += 256) atomicAdd(&lh[dst[i] >> SSHIFT], 1);
  __syncthreads();
  if (t < nsb) blockhist[t * NBLKB + b] = lh[t];
}

// exclusive scan, chunk = blockDim entries; btot==nullptr for top level
__global__ void scan_k(const int* __restrict__ v_in,
    int* __restrict__ excl_out, int* __restrict__ btot, int n) {
  __shared__ int wsum[16];
  int t = threadIdx.x, l = t & 63, w = t >> 6;
  int nw = blockDim.x >> 6;
  int i = blockIdx.x * blockDim.x + t;
  int v = (i < n) ? v_in[i] : 0;
  int orig = v;
  #pragma unroll
  for (int off = 1; off < 64; off <<= 1) {
    int u = __shfl_up(v, off);
    if (l >= off) v += u;
  }
  if (l == 63) wsum[w] = v;
  __syncthreads();
  int add = 0;
  for (int j = 0; j < nw; ++j) if (j < w) add += wsum[j];
  v += add;
  if (i < n) excl_out[i] = v - orig;
  if (t == (int)blockDim.x - 1 && btot != nullptr) btot[blockIdx.x] = v;
}

// ---------- pass B: write edges to exact (block,super) ranges ----------
__global__ __launch_bounds__(256) void stageB_k(const int* __restrict__ src,
    const int* __restrict__ dst, const int* __restrict__ soff,
    const int* __restrict__ boff, unsigned* __restrict__ stage, int E, int nsb) {
  __shared__ int loff[256];
  int b = blockIdx.x, t = threadIdx.x;
  if (t < nsb) loff[t] = soff[t * NBLKB + b] + boff[t];
  __syncthreads();
  int per = (E + gridDim.x - 1) / gridDim.x;
  int s0 = b * per, s1 = min(E, s0 + per);
  for (int i = s0 + t; i < s1; i += 256) {
    int d = dst[i], s = src[i];
    int pos = atomicAdd(&loff[d >> SSHIFT], 1);
    stage[pos] = (unsigned)s | ((unsigned)(d & 255) << 17);  // src<2^17, dloc 8b
  }
}

// ---------- per-super LDS count-sort: stage -> per-node CSR + dinv ----------
__global__ __launch_bounds__(256) void csrsb_k(const unsigned* __restrict__ stage,
    const int* __restrict__ boff, int* __restrict__ row_ptr, int* __restrict__ csr,
    float* __restrict__ dinv, int N, int E, int nsb) {
  __shared__ int cnt[256], off[256], cur[256];
  __shared__ unsigned ebuf[CSR_CAP];
  __shared__ int sbuf[CSR_CAP];
  __shared__ int wsum[4];
  int k = blockIdx.x, t = threadIdx.x, l = t & 63, w = t >> 6;
  cnt[t] = 0; cur[t] = 0;
  __syncthreads();
  int r0 = boff[k];
  int r1 = (k + 1 < nsb) ? boff[k + 1] : E;
  int len = r1 - r0;
  bool fits = len <= CSR_CAP;
  if (fits) {
    for (int i = t; i < len; i += 256) {
      unsigned s = stage[r0 + i];
      ebuf[i] = s;
      atomicAdd(&cnt[s >> 17], 1);
    }
  } else {
    for (int i = r0 + t; i < r1; i += 256) atomicAdd(&cnt[stage[i] >> 17], 1);
  }
  __syncthreads();
  {  // 256-entry exclusive scan (4 waves)
    int v = cnt[t], orig = v;
    #pragma unroll
    for (int o = 1; o < 64; o <<= 1) {
      int u = __shfl_up(v, o);
      if (l >= o) v += u;
    }
    if (l == 63) wsum[w] = v;
    __syncthreads();
    int add = 0;
    #pragma unroll
    for (int j = 0; j < 4; ++j) if (j < w) add += wsum[j];
    int excl = v + add - orig;
    off[t] = excl;
    int n = (k << SSHIFT) + t;
    if (n < N) {
      row_ptr[n] = r0 + excl;
      dinv[n] = rsqrtf((float)(orig + 1));
    }
    if (k == nsb - 1 && t == 255) row_ptr[N] = E;
  }
  __syncthreads();
  if (fits) {
    for (int i = t; i < len; i += 256) {
      unsigned s = ebuf[i];
      int dl = s >> 17;
      int pos = off[dl] + atomicAdd(&cur[dl], 1);
      sbuf[pos] = (int)(s & 0x1FFFF);
    }
    __syncthreads();
    for (int i = t; i < len; i += 256) csr[r0 + i] = sbuf[i];
  } else {
    for (int i = r0 + t; i < r1; i += 256) {
      unsigned s = stage[i];
      int dl = s >> 17;
      int pos = r0 + off[dl] + atomicAdd(&cur[dl], 1);
      csr[pos] = (int)(s & 0x1FFFF);
    }
  }
}

// ---------- g(bf16, slice-major) = dinv[n]*(x@W1) via MFMA split-bf16 ----------
__device__ inline void split8(const float* f, short8v& ah, short8v& al) {
  #pragma unroll
  for (int j = 0; j < 8; ++j) {
    unsigned ua = __float_as_uint(f[j]);
    unsigned hb = (ua + 0x7FFFu + ((ua >> 16) & 1u)) >> 16;
    float fh = __uint_as_float(hb << 16);
    float rl = f[j] - fh;
    unsigned ub = __float_as_uint(rl);
    unsigned lb = (ub + 0x7FFFu + ((ub >> 16) & 1u)) >> 16;
    ah[j] = (short)hb;
    al[j] = (short)lb;
  }
}

__global__ __launch_bounds__(256) void gemm_k(const float* __restrict__ x,
    const float* __restrict__ W, const float* __restrict__ dinv,
    unsigned* __restrict__ gu, int nrows) {
  __shared__ unsigned short Bh[16384];  // [kstep][coltile][lane][j] bf16 bits
  __shared__ unsigned short Bl[16384];
  int t = threadIdx.x, l = t & 63, w = t >> 6;
  for (int idx = t; idx < 16384; idx += 256) {
    int k = idx >> 7, col = idx & 127;
    float wv = W[idx];
    unsigned ua = __float_as_uint(wv);
    unsigned hb = (ua + 0x7FFFu + ((ua >> 16) & 1u)) >> 16;
    float fh = __uint_as_float(hb << 16);
    float rl = wv - fh;
    unsigned ub = __float_as_uint(rl);
    unsigned lb = (ub + 0x7FFFu + ((ub >> 16) & 1u)) >> 16;
    int addr = (((k >> 5) * 8 + (col >> 4)) * 64 +
                (((k >> 3) & 3) * 16 + (col & 15))) * 8 + (k & 7);
    Bh[addr] = (unsigned short)hb;
    Bl[addr] = (unsigned short)lb;
  }
  __syncthreads();

  int row0 = blockIdx.x * 128;
  int ct0 = w * 2;
  float4v acc[8][2];
  #pragma unroll
  for (int i = 0; i < 8; ++i) { acc[i][0] = (float4v)0.f; acc[i][1] = (float4v)0.f; }
  int arow = row0 + (l & 15);
  int kln = (l >> 4) * 8;

  for (int ks = 0; ks < 4; ++ks) {
    short8v bh0 = *(short8v*)&Bh[((ks * 8 + ct0) * 64 + l) * 8];
    short8v bh1 = *(short8v*)&Bh[((ks * 8 + ct0 + 1) * 64 + l) * 8];
    short8v bl0 = *(short8v*)&Bl[((ks * 8 + ct0) * 64 + l) * 8];
    short8v bl1 = *(short8v*)&Bl[((ks * 8 + ct0 + 1) * 64 + l) * 8];
    #pragma unroll
    for (int rt = 0; rt < 8; ++rt) {
      int r = arow + rt * 16;
      const float* xp = &x[(size_t)min(r, nrows - 1) * CIN + ks * 32 + kln];
      float f[8];
      *(float4*)&f[0] = *(const float4*)xp;
      *(float4*)&f[4] = *(const float4*)(xp + 4);
      short8v ah, al;
      split8(f, ah, al);
      acc[rt][0] = __builtin_amdgcn_mfma_f32_16x16x32_bf16(ah, bh0, acc[rt][0], 0, 0, 0);
      acc[rt][1] = __builtin_amdgcn_mfma_f32_16x16x32_bf16(ah, bh1, acc[rt][1], 0, 0, 0);
      acc[rt][0] = __builtin_amdgcn_mfma_f32_16x16x32_bf16(ah, bl0, acc[rt][0], 0, 0, 0);
      acc[rt][1] = __builtin_amdgcn_mfma_f32_16x16x32_bf16(ah, bl1, acc[rt][1], 0, 0, 0);
      acc[rt][0] = __builtin_amdgcn_mfma_f32_16x16x32_bf16(al, bh0, acc[rt][0], 0, 0, 0);
      acc[rt][1] = __builtin_amdgcn_mfma_f32_16x16x32_bf16(al, bh1, acc[rt][1], 0, 0, 0);
    }
  }
  // D col = l&15, row = 4*(l>>4)+reg [HW-verified]; slice = coltile (16 cols)
  #pragma unroll
  for (int rt = 0; rt < 8; ++rt) {
    #pragma unroll
    for (int r = 0; r < 4; ++r) {
      int row = row0 + rt * 16 + (l >> 4) * 4 + r;
      bool ok = row < nrows;
      float dv = ok ? dinv[row] : 0.f;
      #pragma unroll
      for (int c = 0; c < 2; ++c) {
        float val = acc[rt][c][r] * dv;
        float other = __shfl_xor(val, 1);
        int slice = ct0 + c;
        if (ok && !(l & 1))
          gu[((size_t)slice * nrows + row) * 8 + ((l & 15) >> 1)] = pack_bf16x2(val, other);
      }
    }
  }
}

// ---------- propagate-1: XCD-sliced gather + partial projection ----------
__global__ __launch_bounds__(256) void prop1s_k(const unsigned* __restrict__ gs,
    const int* __restrict__ row_ptr, const int* __restrict__ csr,
    const float* __restrict__ dinv, const float* __restrict__ b1,
    const float* __restrict__ Wout, float* __restrict__ g2part,
    int N, int waves_per_slice) {
  int slice = blockIdx.x & 7;          // XCD round-robin
  int chunk = blockIdx.x >> 3;
  int t = threadIdx.x, l = t & 63, w = t >> 6;
  int gi = l >> 3, il = l & 7;         // gi: edge-group / output j; il: col pair
  int c0 = slice * 16 + 2 * il, c1 = c0 + 1;
  float wa = Wout[(gi >> 1) * 256 + c0 * 2 + (gi & 1)];
  float wb = Wout[(gi >> 1) * 256 + c1 * 2 + (gi & 1)];
  float ba = b1[c0], bb2 = b1[c1];
  const unsigned* gb = gs + (size_t)slice * N * 8 + il;
  float* gp = g2part + (size_t)slice * N * 8;

  int wsl = chunk * 4 + w;
  for (int n = wsl; n < N; n += waves_per_slice) {
    int start = row_ptr[n], end = row_ptr[n + 1];
    float d = dinv[n];
    float ax = 0.f, ay = 0.f;
    for (int base = start; base < end; base += 64) {
      int cnt = min(64, end - base);
      int eb = (base + l < end) ? csr[base + l] : 0;
      int i = 0;
      for (; i + 16 <= cnt; i += 16) {
        int sa = __shfl(eb, i + gi);
        int sb = __shfl(eb, i + 8 + gi);
        unsigned ua = gb[(size_t)sa * 8];
        unsigned ub = gb[(size_t)sb * 8];
        ax += bf_lo(ua) + bf_lo(ub);
        ay += bf_hi(ua) + bf_hi(ub);
      }
      for (; i + 8 <= cnt; i += 8) {
        int sa = __shfl(eb, i + gi);
        unsigned ua = gb[(size_t)sa * 8];
        ax += bf_lo(ua); ay += bf_hi(ua);
      }
      if (i < cnt) {
        int idx = i + gi;
        int sa = __shfl(eb, idx < cnt ? idx : i);
        if (idx < cnt) {
          unsigned ua = gb[(size_t)sa * 8];
          ax += bf_lo(ua); ay += bf_hi(ua);
        }
      }
    }
    // reduce over the 8 edge-groups, THEN add self-loop exactly once
    ax += __shfl_xor(ax, 8); ax += __shfl_xor(ax, 16); ax += __shfl_xor(ax, 32);
    ay += __shfl_xor(ay, 8); ay += __shfl_xor(ay, 16); ay += __shfl_xor(ay, 32);
    unsigned us = gb[(size_t)n * 8];   // self-loop (dinv folded in g)
    ax += bf_lo(us); ay += bf_hi(us);
    float y0 = fmaxf(fmaf(ax, d, ba), 0.f);
    float y1 = fmaxf(fmaf(ay, d, bb2), 0.f);
    float c = fmaf(y0, wa, y1 * wb);
    c += __shfl_xor(c, 1); c += __shfl_xor(c, 2); c += __shfl_xor(c, 4);
    if (il == 0) gp[(size_t)n * 8 + gi] = c;
  }
}

// ---------- finalize: sum slice partials, apply dinv, pack bf16 ----------
__global__ __launch_bounds__(256) void finalize_k(const float* __restrict__ g2part,
    const float* __restrict__ dinv, unsigned* __restrict__ g2w, int N) {
  int tid = blockIdx.x * 256 + threadIdx.x;
  if (tid >= N * 4) return;
  int n = tid >> 2, jp = tid & 3;
  float s0 = 0.f, s1 = 0.f;
  #pragma unroll
  for (int s = 0; s < 8; ++s) {
    const float* p = &g2part[((size_t)s * N + n) * 8 + jp * 2];
    s0 += p[0]; s1 += p[1];
  }
  float d = dinv[n];
  g2w[n * 4 + jp] = pack_bf16x2(d * s0, d * s1);
}

// ---------- propagate-2: 2 threads/node, uint2 bf16x4 per edge ----------
__global__ __launch_bounds__(256) void prop2_k(const uint2* __restrict__ g2v,
    const int* __restrict__ row_ptr, const int* __restrict__ csr,
    const float* __restrict__ dinv, const float* __restrict__ bout,
    float* __restrict__ out, int N) {
  int tid = blockIdx.x * 256 + threadIdx.x;
  int n = tid >> 1, hf = tid & 1;
  if (n >= N) return;
  uint2 us = g2v[n * 2 + hf];      // self-loop
  float a0 = bf_lo(us.x), a1 = bf_hi(us.x);
  float a2 = bf_lo(us.y), a3 = bf_hi(us.y);
  int e = row_ptr[n], e1 = row_ptr[n + 1];
  for (; e + 4 <= e1; e += 4) {
    int i0 = csr[e], i1 = csr[e + 1], i2 = csr[e + 2], i3 = csr[e + 3];
    uint2 u0 = g2v[i0 * 2 + hf], u1 = g2v[i1 * 2 + hf];
    uint2 u2 = g2v[i2 * 2 + hf], u3 = g2v[i3 * 2 + hf];
    a0 += (bf_lo(u0.x) + bf_lo(u1.x)) + (bf_lo(u2.x) + bf_lo(u3.x));
    a1 += (bf_hi(u0.x) + bf_hi(u1.x)) + (bf_hi(u2.x) + bf_hi(u3.x));
    a2 += (bf_lo(u0.y) + bf_lo(u1.y)) + (bf_lo(u2.y) + bf_lo(u3.y));
    a3 += (bf_hi(u0.y) + bf_hi(u1.y)) + (bf_hi(u2.y) + bf_hi(u3.y));
  }
  for (; e < e1; ++e) {
    uint2 u = g2v[csr[e] * 2 + hf];
    a0 += bf_lo(u.x); a1 += bf_hi(u.x);
    a2 += bf_lo(u.y); a3 += bf_hi(u.y);
  }
  float d = dinv[n];
  float2 o0 = make_float2(fmaf(d, a0, bout[hf * 4 + 0]), fmaf(d, a1, bout[hf * 4 + 1]));
  float2 o1 = make_float2(fmaf(d, a2, bout[hf * 4 + 2]), fmaf(d, a3, bout[hf * 4 + 3]));
  *(float2*)&out[(size_t)(hf * 2 + 0) * (2 * N) + 2 * n] = o0;
  *(float2*)&out[(size_t)(hf * 2 + 1) * (2 * N) + 2 * n] = o1;
}

extern "C" void kernel_launch(void* const* d_in, const int* in_sizes, int n_in,
                              void* d_out, int out_size, void* d_ws, size_t ws_size,
                              hipStream_t stream) {
  const float* x    = (const float*)d_in[0];
  const int*   ei   = (const int*)d_in[1];
  const float* W1   = (const float*)d_in[2];
  const float* b1   = (const float*)d_in[3];
  const float* Wout = (const float*)d_in[4];
  const float* bout = (const float*)d_in[5];
  float* out = (float*)d_out;

  const int N = in_sizes[0] / CIN;       // 50000
  const int E = in_sizes[1] / 2;         // 1600000
  const int* srcp = ei;
  const int* dstp = ei + E;
  const int NSB = (N + 255) >> SSHIFT;   // 196 super-buckets
  const int NSC = NSB * NBLKB;           // 50176 scan entries

  char* ws = (char*)d_ws;
  size_t off = 0;
  auto alloc = [&](size_t bytes) -> void* {
    void* p = ws + off;
    off = (off + bytes + 511) & ~(size_t)511;
    return p;
  };
  unsigned*       gu        = (unsigned*)alloc((size_t)N * 64 * 4);      // bf16 g, slice-major
  float*          g2part    = (float*)alloc((size_t)8 * N * 8 * 4);      // fp32 partials
  unsigned short* g2u       = (unsigned short*)alloc((size_t)N * 8 * 2); // bf16 g2
  float*          dinv      = (float*)alloc((size_t)N * 4);
  int*            blockhist = (int*)alloc((size_t)NSC * 4);
  int*            soff      = (int*)alloc((size_t)NSC * 4);
  int*            btot      = (int*)alloc(256 * 4);
  int*            boff      = (int*)alloc(256 * 4);
  int*            row_ptr   = (int*)alloc((size_t)(N + 1) * 4);
  int*            csr       = (int*)alloc((size_t)E * 4);
  unsigned*       stage     = (unsigned*)alloc((size_t)E * 4);
  (void)ws_size; (void)n_in; (void)out_size;

  histsb_k<<<NBLKB, 256, 0, stream>>>(dstp, blockhist, E, NSB);
  scan_k<<<NSB, 256, 0, stream>>>(blockhist, soff, btot, NSC);   // level 1
  scan_k<<<1, 256, 0, stream>>>(btot, boff, nullptr, NSB);       // level 2
  stageB_k<<<NBLKB, 256, 0, stream>>>(srcp, dstp, soff, boff, stage, E, NSB);
  csrsb_k<<<NSB, 256, 0, stream>>>(stage, boff, row_ptr, csr, dinv, N, E, NSB);

  gemm_k<<<(N + 127) / 128, 256, 0, stream>>>(x, W1, dinv, gu, N);

  const int P1_BLOCKS = 2048;            // 256 chunks x 8 slices
  prop1s_k<<<P1_BLOCKS, 256, 0, stream>>>(gu, row_ptr, csr, dinv, b1, Wout,
                                          g2part, N, (P1_BLOCKS / 8) * 4);
  finalize_k<<<(N * 4 + 255) / 256, 256, 0, stream>>>(g2part, dinv, (unsigned*)g2u, N);
  prop2_k<<<(2 * N + 255) / 256, 256, 0, stream>>>((const uint2*)g2u, row_ptr, csr,
                                                   dinv, bout, out, N);
}